// Round 3
// baseline (117.338 us; speedup 1.0000x reference)
//
#include <hip/hip_runtime.h>
#include <hip/hip_bf16.h>

#define BATCH 32
#define SEQ   1024
#define DCH   256
#define TMAX  4096
#define MROWS (BATCH * SEQ)
#define EPS   1e-5f

typedef __attribute__((ext_vector_type(8))) short s16x8;   // 8 bf16 in 4 VGPRs
typedef __attribute__((ext_vector_type(4))) float f32x4;

#define NSTEPS 24
#define WROW_B 80                       // 40 bf16 per col-row (32 used + pad)
#define WTILE_B (256 * WROW_B)          // 20480 B per K-step tile
#define XST_B  (66 * 512)               // 33792 B X tile (66 rows x 256 bf16)
#define LDS_TOTAL (XST_B + 2 * WTILE_B) // 74752 B -> 2 blocks/CU

#define CONV_BLOCKS 512
#define REG_PER_KERNEL 1024             // regulate blocks appended per conv kernel
#define GRID_TOTAL 1536                 // conv every 3rd block

__device__ __forceinline__ short f2bf(float f) {
    union { float f; unsigned u; } x; x.f = f;
    unsigned r = x.u + 0x7fffu + ((x.u >> 16) & 1u);   // RNE
    return (short)(r >> 16);
}

__device__ __forceinline__ void gload16(const void* g, void* l) {
    __builtin_amdgcn_global_load_lds(
        (const __attribute__((address_space(1))) unsigned int*)g,
        (__attribute__((address_space(3))) unsigned int*)l, 16, 0, 0);
}

// ---------------------------------------------------------------------------
// Prep: blocks 0..47 -> weight transpose/pad to bf16; blocks 48..79 -> cumsum.
// Wp layout [24][256 cols][40] bf16.
// ---------------------------------------------------------------------------
__global__ __launch_bounds__(256) void prep_kernel(
    const float* __restrict__ W1, const float* __restrict__ W2,
    short* __restrict__ Wp1, short* __restrict__ Wp2,
    const int* __restrict__ target, int* __restrict__ cum)
{
    const int bx  = blockIdx.x;
    const int tid = threadIdx.x;
    if (bx < 48) {
        const int s = bx % NSTEPS;
        const float* W = (bx < NSTEPS) ? W1 : W2;
        short* out = (bx < NSTEPS) ? Wp1 : Wp2;
        const int n  = tid;
        const int ko = s >> 3;
        const int cb = (s & 7) * 32;
        short tmp[40];
        #pragma unroll
        for (int kk = 0; kk < 32; ++kk)
            tmp[kk] = f2bf(W[(size_t)(ko * 256 + cb + kk) * 256 + n]);
        #pragma unroll
        for (int kk = 32; kk < 40; ++kk) tmp[kk] = 0;
        short* dst = out + ((size_t)s * 256 + n) * 40;
        #pragma unroll
        for (int i = 0; i < 5; ++i)
            *(s16x8*)(dst + i * 8) = *(const s16x8*)(tmp + i * 8);
    } else {
        const int b = bx - 48;
        const int base = b * SEQ + tid * 4;
        int vals[4];
        int s = 0;
        #pragma unroll
        for (int j = 0; j < 4; ++j) {
            s += target[base + j] + 1;   // alpha == 1.0 -> reps = target + 1
            vals[j] = s;
        }
        const int lane = tid & 63;
        int tot = s;
        #pragma unroll
        for (int off = 1; off < 64; off <<= 1) {
            int t = __shfl_up(tot, off, 64);
            if (lane >= off) tot += t;
        }
        __shared__ int wsum[4];
        const int wid = tid >> 6;
        if (lane == 63) wsum[wid] = tot;
        __syncthreads();
        int woff = 0;
        for (int w = 0; w < wid; ++w) woff += wsum[w];
        const int thr_excl = tot - s + woff;
        #pragma unroll
        for (int j = 0; j < 4; ++j) cum[base + j] = thr_excl + vals[j];
    }
}

// ---------------------------------------------------------------------------
// Fused kernel: blockIdx%3==0 -> conv1d+LN(+head) MFMA block (64 rows x 256),
// else -> length-regulate block (64 output frames x 256 ch).
// HEAD=false: conv Y = h1 bf16, regulate frames [0, 65536)
// HEAD=true : conv Y = dur_pred f32, regulate frames [65536, 131072)
// ---------------------------------------------------------------------------
template <bool HEAD>
__global__ __launch_bounds__(256, 2) void conv_reg(
    const void* __restrict__ Xsrc,      // f32 enc (HEAD=0) or bf16 h1 (HEAD=1)
    const float* __restrict__ mask,     // [MROWS]
    const short* __restrict__ Wp,       // prepped [24][256][40] bf16
    const float* __restrict__ bias,
    const float* __restrict__ gam,
    const float* __restrict__ bet,
    const float* __restrict__ Wl,       // [256] (HEAD only)
    const float* __restrict__ bl,       // [1]   (HEAD only)
    void* __restrict__ Y,
    const float* __restrict__ enc,      // [BATCH][SEQ][256] f32
    const int*  __restrict__ cum,       // [BATCH][SEQ]
    float* __restrict__ out_main,       // [BATCH][TMAX][256]
    float* __restrict__ out_pos)        // [BATCH][TMAX]
{
    __shared__ __align__(16) char lds[LDS_TOTAL];
    const int tid = threadIdx.x;
    const int bx  = blockIdx.x;

    if (bx % 3 != 0) {
        // =================== length-regulate block ===================
        const int r  = (bx - bx / 3 - 1) + (HEAD ? REG_PER_KERNEL : 0); // 0..2047
        const int b  = r >> 6;
        const int t0 = (r & 63) * 64;
        int* sidx   = (int*)lds;
        int* svalid = (int*)(lds + 256);
        const int* c = cum + b * SEQ;
        if (tid < 64) {
            const int t = t0 + tid;
            const int total = c[SEQ - 1];
            int lo = 0, hi = SEQ;
            while (lo < hi) {
                const int mid = (lo + hi) >> 1;
                if (c[mid] <= t) lo = mid + 1; else hi = mid;
            }
            const int valid = (t < total) ? 1 : 0;
            sidx[tid]   = lo < (SEQ - 1) ? lo : (SEQ - 1);
            svalid[tid] = valid;
            out_pos[b * TMAX + t] = valid ? (float)(t + 1) : 0.f;
        }
        __syncthreads();
        const int f4 = (tid & 63) * 4;
        const int rg = tid >> 6;
        #pragma unroll
        for (int g = 0; g < 16; ++g) {
            const int tt = g * 4 + rg;
            float4 v = make_float4(0.f, 0.f, 0.f, 0.f);
            if (svalid[tt])
                v = *reinterpret_cast<const float4*>(enc + (size_t)(b * SEQ + sidx[tt]) * 256 + f4);
            *reinterpret_cast<float4*>(out_main + (size_t)(b * TMAX + t0 + tt) * 256 + f4) = v;
        }
        return;
    }

    // ======================= conv block =======================
    char* const Xst = lds;
    char* const W0  = lds + XST_B;

    const int lane = tid & 63;
    const int wv   = tid >> 6;          // wave 0..3 -> cols wv*64..+63
    const int cl   = lane & 15;
    const int q    = lane >> 4;
    const int m0   = (bx / 3) * 64;
    const int blo  = m0 & ~(SEQ - 1);
    const int bhi  = blo + SEQ;

    // ---- stage X tile: rows m0-1 .. m0+64 (halo), XOR-swizzled 16B chunks ----
    for (int t = tid; t < 66 * 32; t += 256) {
        const int r  = t >> 5;
        const int ch = t & 31;
        const int grow = m0 - 1 + r;
        s16x8 v = {0, 0, 0, 0, 0, 0, 0, 0};
        if (grow >= blo && grow < bhi) {
            if (!HEAD) {
                const float* xf = (const float*)Xsrc + (size_t)grow * DCH + ch * 8;
                const float4 f0 = *(const float4*)xf;
                const float4 f1 = *(const float4*)(xf + 4);
                const float mk = mask[grow];
                v[0] = f2bf(f0.x * mk); v[1] = f2bf(f0.y * mk);
                v[2] = f2bf(f0.z * mk); v[3] = f2bf(f0.w * mk);
                v[4] = f2bf(f1.x * mk); v[5] = f2bf(f1.y * mk);
                v[6] = f2bf(f1.z * mk); v[7] = f2bf(f1.w * mk);
            } else {
                v = *(const s16x8*)((const char*)Xsrc + (size_t)grow * 512 + ch * 16);
            }
        }
        *(s16x8*)(Xst + r * 512 + ((ch ^ (r & 7)) << 4)) = v;
    }

    // ---- stage W step 0 ----
    {
        const char* src = (const char*)Wp + wv * 5120 + lane * 16;
        char* dst = W0 + wv * 5120;
        #pragma unroll
        for (int i = 0; i < 5; ++i)
            gload16(src + i * 1024, dst + i * 1024);
    }

    // ---- init acc with conv bias ----
    f32x4 acc[4][4];
    #pragma unroll
    for (int nc = 0; nc < 4; ++nc) {
        const float b = bias[wv * 64 + nc * 16 + cl];
        #pragma unroll
        for (int mr = 0; mr < 4; ++mr) acc[mr][nc] = (f32x4){b, b, b, b};
    }

    __syncthreads();

    // ---- K loop ----
    for (int s = 0; s < NSTEPS; ++s) {
        char* const wbuf = W0 + (s & 1) * WTILE_B;
        if (s + 1 < NSTEPS) {
            const char* src = (const char*)Wp + (size_t)(s + 1) * WTILE_B + wv * 5120 + lane * 16;
            char* dst = W0 + ((s + 1) & 1) * WTILE_B + wv * 5120;
            #pragma unroll
            for (int i = 0; i < 5; ++i)
                gload16(src + i * 1024, dst + i * 1024);
        }
        const int ko  = s >> 3;
        const int chb = (s & 7) * 4 + q;
        s16x8 a[4], bb[4];
        #pragma unroll
        for (int mr = 0; mr < 4; ++mr) {
            const int tr = mr * 16 + cl + ko;
            a[mr] = *(const s16x8*)(Xst + tr * 512 + ((chb ^ (tr & 7)) << 4));
        }
        #pragma unroll
        for (int nc = 0; nc < 4; ++nc) {
            const int col = wv * 64 + nc * 16 + cl;
            bb[nc] = *(const s16x8*)(wbuf + col * WROW_B + (q << 4));
        }
        #pragma unroll
        for (int mr = 0; mr < 4; ++mr)
            #pragma unroll
            for (int nc = 0; nc < 4; ++nc)
                acc[mr][nc] = __builtin_amdgcn_mfma_f32_16x16x32_bf16(
                    a[mr], bb[nc], acc[mr][nc], 0, 0, 0);
        __syncthreads();
    }

    // ---- LayerNorm stats ----
    float* red   = (float*)(lds + XST_B);          // [64][4 waves][2]
    float* stats = (float*)(lds + XST_B + 2048);   // [64][2]
    #pragma unroll
    for (int mr = 0; mr < 4; ++mr) {
        #pragma unroll
        for (int rg = 0; rg < 4; ++rg) {
            float s1 = 0.f, s2 = 0.f;
            #pragma unroll
            for (int nc = 0; nc < 4; ++nc) {
                const float v = acc[mr][nc][rg];
                s1 += v; s2 += v * v;
            }
            #pragma unroll
            for (int m = 1; m < 16; m <<= 1) {
                s1 += __shfl_xor(s1, m, 64);
                s2 += __shfl_xor(s2, m, 64);
            }
            if (cl == 0) {
                const int r = mr * 16 + q * 4 + rg;
                red[(r * 4 + wv) * 2]     = s1;
                red[(r * 4 + wv) * 2 + 1] = s2;
            }
        }
    }
    __syncthreads();
    if (tid < 64) {
        const float s1 = red[tid*8] + red[tid*8+2] + red[tid*8+4] + red[tid*8+6];
        const float s2 = red[tid*8+1] + red[tid*8+3] + red[tid*8+5] + red[tid*8+7];
        const float mean = s1 * (1.f / 256.f);
        const float var  = s2 * (1.f / 256.f) - mean * mean;
        stats[tid * 2]     = mean;
        stats[tid * 2 + 1] = rsqrtf(var + EPS);
    }
    __syncthreads();

    if (!HEAD) {
        float gv[4], bv[4];
        #pragma unroll
        for (int nc = 0; nc < 4; ++nc) {
            const int col = wv * 64 + nc * 16 + cl;
            gv[nc] = gam[col]; bv[nc] = bet[col];
        }
        short* y = (short*)Y;
        #pragma unroll
        for (int mr = 0; mr < 4; ++mr) {
            #pragma unroll
            for (int rg = 0; rg < 4; ++rg) {
                const int r = mr * 16 + q * 4 + rg;
                const float2 ms = *(const float2*)(stats + r * 2);
                #pragma unroll
                for (int nc = 0; nc < 4; ++nc) {
                    const int col = wv * 64 + nc * 16 + cl;
                    float v = (acc[mr][nc][rg] - ms.x) * ms.y * gv[nc] + bv[nc];
                    y[(size_t)(m0 + r) * DCH + col] = f2bf(fmaxf(v, 0.f));
                }
            }
        }
    } else {
        float gv[4], bv[4], wl[4];
        #pragma unroll
        for (int nc = 0; nc < 4; ++nc) {
            const int col = wv * 64 + nc * 16 + cl;
            gv[nc] = gam[col]; bv[nc] = bet[col]; wl[nc] = Wl[col];
        }
        float* red2 = (float*)(lds + XST_B + 4096);   // [64][4]
        #pragma unroll
        for (int mr = 0; mr < 4; ++mr) {
            #pragma unroll
            for (int rg = 0; rg < 4; ++rg) {
                const int r = mr * 16 + q * 4 + rg;
                const float2 ms = *(const float2*)(stats + r * 2);
                float p = 0.f;
                #pragma unroll
                for (int nc = 0; nc < 4; ++nc) {
                    float v = (acc[mr][nc][rg] - ms.x) * ms.y * gv[nc] + bv[nc];
                    p += fmaxf(v, 0.f) * wl[nc];
                }
                #pragma unroll
                for (int m = 1; m < 16; m <<= 1) p += __shfl_xor(p, m, 64);
                if (cl == 0) red2[r * 4 + wv] = p;
            }
        }
        __syncthreads();
        if (tid < 64) {
            float d = red2[tid*4] + red2[tid*4+1] + red2[tid*4+2] + red2[tid*4+3] + bl[0];
            d *= mask[m0 + tid];
            ((float*)Y)[m0 + tid] = fmaxf(d, 0.f);
        }
    }
}

// ---------------------------------------------------------------------------
extern "C" void kernel_launch(void* const* d_in, const int* in_sizes, int n_in,
                              void* d_out, int out_size, void* d_ws, size_t ws_size,
                              hipStream_t stream) {
    const float* enc   = (const float*)d_in[0];
    const float* mask  = (const float*)d_in[1];
    const int*   target= (const int*)  d_in[2];
    const float* W1    = (const float*)d_in[4];
    const float* b1    = (const float*)d_in[5];
    const float* g1    = (const float*)d_in[6];
    const float* beta1 = (const float*)d_in[7];
    const float* W2    = (const float*)d_in[8];
    const float* b2    = (const float*)d_in[9];
    const float* g2    = (const float*)d_in[10];
    const float* beta2 = (const float*)d_in[11];
    const float* Wl    = (const float*)d_in[12];
    const float* bl    = (const float*)d_in[13];

    float* outF = (float*)d_out;
    float* out_main = outF;                               // 32*4096*256
    float* out_pos  = outF + (size_t)BATCH * TMAX * DCH;  // 32*4096
    float* out_dur  = out_pos + (size_t)BATCH * TMAX;     // 32*1024

    char* ws = (char*)d_ws;
    short* h1  = (short*)ws;                                   // 16 MB bf16
    short* Wp1 = (short*)(ws + (size_t)MROWS * DCH * 2);       // 480 KB
    short* Wp2 = (short*)(ws + (size_t)MROWS * DCH * 2 + NSTEPS * WTILE_B);
    int*   cum = (int*)  (ws + (size_t)MROWS * DCH * 2 + 2 * (size_t)NSTEPS * WTILE_B);

    prep_kernel<<<80, 256, 0, stream>>>(W1, W2, Wp1, Wp2, target, cum);
    conv_reg<false><<<GRID_TOTAL, 256, 0, stream>>>(
        enc, mask, Wp1, b1, g1, beta1, nullptr, nullptr, h1,
        enc, cum, out_main, out_pos);
    conv_reg<true><<<GRID_TOTAL, 256, 0, stream>>>(
        h1, mask, Wp2, b2, g2, beta2, Wl, bl, out_dur,
        enc, cum, out_main, out_pos);
}

// Round 4
// 82.255 us; speedup vs baseline: 1.4265x; 1.4265x over previous
//
#include <hip/hip_runtime.h>
#include <hip/hip_bf16.h>

#define BATCH 32
#define SEQ   1024
#define DCH   256
#define TMAX  4096
#define MROWS (BATCH * SEQ)
#define EPS   1e-5f

typedef __attribute__((ext_vector_type(8))) short s16x8;   // 8 bf16 in 4 VGPRs
typedef __attribute__((ext_vector_type(4))) float f32x4;

#define NSTEPS 24
// Wp layout: [s][wv][nc][lane] 16B chunks -> short offset
//   s*8192 + wv*2048 + nc*512 + lane*8      (lane = q*16+cl)
#define WP_SHORTS (NSTEPS * 8192)            // 196608 shorts = 393216 B / layer

#define XST_B   33792                        // 66 rows x 512 B  (X tile)
#define RED_OFF   33792                      // [64][4][2] f32 = 2048 B
#define STATS_OFF 35840                      // [64][2]   f32 = 512 B
#define RED2_OFF  36352                      // [64][4]   f32 = 1024 B
#define LDS_TOTAL 37376
#define XT2_STRIDE 528                       // transpose-out row stride (bytes)

__device__ __forceinline__ short f2bf(float f) {
    union { float f; unsigned u; } x; x.f = f;
    unsigned r = x.u + 0x7fffu + ((x.u >> 16) & 1u);   // RNE
    return (short)(r >> 16);
}

// ---------------------------------------------------------------------------
// Prep: blocks 0..47 -> weight bf16 repack (coalesced B-frag layout);
//       blocks 48..79 -> per-batch cumsum of reps = target + 1.
// ---------------------------------------------------------------------------
__global__ __launch_bounds__(256) void prep_kernel(
    const float* __restrict__ W1, const float* __restrict__ W2,
    short* __restrict__ Wp1, short* __restrict__ Wp2,
    const int* __restrict__ target, int* __restrict__ cum)
{
    const int bx  = blockIdx.x;
    const int tid = threadIdx.x;
    if (bx < 48) {
        const int s = bx % NSTEPS;
        const float* W = (bx < NSTEPS) ? W1 : W2;
        short* out = (bx < NSTEPS) ? Wp1 : Wp2;
        const int n  = tid;                  // output col 0..255
        const int wv = n >> 6;
        const int nc = (n >> 4) & 3;
        const int cl = n & 15;
        const int ko = s >> 3;
        const int cb = (s & 7) * 32;
        #pragma unroll
        for (int q = 0; q < 4; ++q) {
            short v[8];
            #pragma unroll
            for (int j = 0; j < 8; ++j)
                v[j] = f2bf(W[(size_t)(ko * 256 + cb + q * 8 + j) * 256 + n]);
            short* dst = out + s * 8192 + wv * 2048 + nc * 512 + (q * 16 + cl) * 8;
            *(s16x8*)dst = *(const s16x8*)v;
        }
    } else {
        const int b = bx - 48;
        const int base = b * SEQ + tid * 4;
        int vals[4];
        int s = 0;
        #pragma unroll
        for (int j = 0; j < 4; ++j) {
            s += target[base + j] + 1;   // alpha == 1.0 -> reps = target + 1
            vals[j] = s;
        }
        const int lane = tid & 63;
        int tot = s;
        #pragma unroll
        for (int off = 1; off < 64; off <<= 1) {
            int t = __shfl_up(tot, off, 64);
            if (lane >= off) tot += t;
        }
        __shared__ int wsum[4];
        const int wid = tid >> 6;
        if (lane == 63) wsum[wid] = tot;
        __syncthreads();
        int woff = 0;
        for (int w = 0; w < wid; ++w) woff += wsum[w];
        const int thr_excl = tot - s + woff;
        #pragma unroll
        for (int j = 0; j < 4; ++j) cum[base + j] = thr_excl + vals[j];
    }
}

// ---------------------------------------------------------------------------
// Fused conv1d(K=3,pad=1,per-batch) + bias + LayerNorm + ReLU (MFMA bf16).
// B-frags stream straight from global (L1/L2-resident Wp) with 1-step register
// prefetch; K-loop is barrier-free (X tile is read-only after one barrier).
// HEAD=false: Y = h1 bf16 (via LDS-transposed coalesced stores)
// HEAD=true : Y = dur_pred f32 (fused Wl head)
// ---------------------------------------------------------------------------
template <bool HEAD>
__global__ __launch_bounds__(256, 2) void conv_mfma(
    const void* __restrict__ Xsrc,      // f32 enc (HEAD=0) or bf16 h1 (HEAD=1)
    const float* __restrict__ mask,     // [MROWS]
    const short* __restrict__ Wp,       // repacked bf16 weights
    const float* __restrict__ bias,
    const float* __restrict__ gam,
    const float* __restrict__ bet,
    const float* __restrict__ Wl,       // [256] (HEAD only)
    const float* __restrict__ bl,       // [1]   (HEAD only)
    void* __restrict__ Y)
{
    __shared__ __align__(16) char lds[LDS_TOTAL];
    char* const Xst = lds;

    const int tid  = threadIdx.x;
    const int lane = tid & 63;
    const int wv   = tid >> 6;          // wave 0..3 -> cols wv*64..+63
    const int cl   = lane & 15;
    const int q    = lane >> 4;
    const int m0   = blockIdx.x * 64;
    const int blo  = m0 & ~(SEQ - 1);
    const int bhi  = blo + SEQ;

    // ---- stage X tile: rows m0-1 .. m0+64 (halo), XOR-swizzled 16B chunks ----
    for (int t = tid; t < 66 * 32; t += 256) {
        const int r  = t >> 5;
        const int ch = t & 31;
        const int grow = m0 - 1 + r;
        s16x8 v = {0, 0, 0, 0, 0, 0, 0, 0};
        if (grow >= blo && grow < bhi) {
            if (!HEAD) {
                const float* xf = (const float*)Xsrc + (size_t)grow * DCH + ch * 8;
                const float4 f0 = *(const float4*)xf;
                const float4 f1 = *(const float4*)(xf + 4);
                const float mk = mask[grow];
                v[0] = f2bf(f0.x * mk); v[1] = f2bf(f0.y * mk);
                v[2] = f2bf(f0.z * mk); v[3] = f2bf(f0.w * mk);
                v[4] = f2bf(f1.x * mk); v[5] = f2bf(f1.y * mk);
                v[6] = f2bf(f1.z * mk); v[7] = f2bf(f1.w * mk);
            } else {
                v = *(const s16x8*)((const char*)Xsrc + (size_t)grow * 512 + ch * 16);
            }
        }
        *(s16x8*)(Xst + r * 512 + ((ch ^ (r & 7)) << 4)) = v;
    }

    // ---- init acc with conv bias ----
    f32x4 acc[4][4];
    #pragma unroll
    for (int nc = 0; nc < 4; ++nc) {
        const float b = bias[wv * 64 + nc * 16 + cl];
        #pragma unroll
        for (int mr = 0; mr < 4; ++mr) acc[mr][nc] = (f32x4){b, b, b, b};
    }

    // ---- B-frag prefetch for step 0 (global, coalesced dwordx4) ----
    const short* wbase = Wp + wv * 2048 + lane * 8;
    s16x8 bb[4];
    #pragma unroll
    for (int nc = 0; nc < 4; ++nc)
        bb[nc] = *(const s16x8*)(wbase + nc * 512);

    __syncthreads();   // X tile ready; only barrier before epilogue

    // ---- K loop: 24 steps, no barriers, B prefetched one step ahead ----
    for (int s = 0; s < NSTEPS; ++s) {
        const int sp = (s + 1 < NSTEPS) ? s + 1 : s;
        s16x8 bn[4];
        #pragma unroll
        for (int nc = 0; nc < 4; ++nc)
            bn[nc] = *(const s16x8*)(wbase + sp * 8192 + nc * 512);
        const int ko  = s >> 3;
        const int chb = (s & 7) * 4 + q;
        s16x8 a[4];
        #pragma unroll
        for (int mr = 0; mr < 4; ++mr) {
            const int tr = mr * 16 + cl + ko;
            a[mr] = *(const s16x8*)(Xst + tr * 512 + ((chb ^ (tr & 7)) << 4));
        }
        #pragma unroll
        for (int mr = 0; mr < 4; ++mr)
            #pragma unroll
            for (int nc = 0; nc < 4; ++nc)
                acc[mr][nc] = __builtin_amdgcn_mfma_f32_16x16x32_bf16(
                    a[mr], bb[nc], acc[mr][nc], 0, 0, 0);
        #pragma unroll
        for (int nc = 0; nc < 4; ++nc) bb[nc] = bn[nc];
    }

    // ---- LayerNorm stats: 16-lane shfl + cross-wave LDS reduction ----
    float* red   = (float*)(lds + RED_OFF);
    float* stats = (float*)(lds + STATS_OFF);
    #pragma unroll
    for (int mr = 0; mr < 4; ++mr) {
        #pragma unroll
        for (int rg = 0; rg < 4; ++rg) {
            float s1 = 0.f, s2 = 0.f;
            #pragma unroll
            for (int nc = 0; nc < 4; ++nc) {
                const float v = acc[mr][nc][rg];
                s1 += v; s2 += v * v;
            }
            #pragma unroll
            for (int m = 1; m < 16; m <<= 1) {
                s1 += __shfl_xor(s1, m, 64);
                s2 += __shfl_xor(s2, m, 64);
            }
            if (cl == 0) {
                const int r = mr * 16 + q * 4 + rg;
                red[(r * 4 + wv) * 2]     = s1;
                red[(r * 4 + wv) * 2 + 1] = s2;
            }
        }
    }
    __syncthreads();   // also: all waves done reading Xst
    if (tid < 64) {
        const float s1 = red[tid*8] + red[tid*8+2] + red[tid*8+4] + red[tid*8+6];
        const float s2 = red[tid*8+1] + red[tid*8+3] + red[tid*8+5] + red[tid*8+7];
        const float mean = s1 * (1.f / 256.f);
        const float var  = s2 * (1.f / 256.f) - mean * mean;
        stats[tid * 2]     = mean;
        stats[tid * 2 + 1] = rsqrtf(var + EPS);
    }
    __syncthreads();

    if (!HEAD) {
        float gv[4], bv[4];
        #pragma unroll
        for (int nc = 0; nc < 4; ++nc) {
            const int col = wv * 64 + nc * 16 + cl;
            gv[nc] = gam[col]; bv[nc] = bet[col];
        }
        // normalized bf16 -> LDS transpose buffer (reuses Xst region)
        #pragma unroll
        for (int mr = 0; mr < 4; ++mr) {
            #pragma unroll
            for (int rg = 0; rg < 4; ++rg) {
                const int r = mr * 16 + q * 4 + rg;
                const float2 ms = *(const float2*)(stats + r * 2);
                #pragma unroll
                for (int nc = 0; nc < 4; ++nc) {
                    const int col = wv * 64 + nc * 16 + cl;
                    float v = (acc[mr][nc][rg] - ms.x) * ms.y * gv[nc] + bv[nc];
                    *(short*)(lds + r * XT2_STRIDE + col * 2) = f2bf(fmaxf(v, 0.f));
                }
            }
        }
        __syncthreads();
        // coalesced 16B copy-out
        short* y = (short*)Y;
        #pragma unroll
        for (int i = 0; i < 8; ++i) {
            const int t  = tid + i * 256;     // 0..2047
            const int r  = t >> 5;
            const int ch = t & 31;
            const s16x8 v = *(const s16x8*)(lds + r * XT2_STRIDE + ch * 16);
            *(s16x8*)(y + (size_t)(m0 + r) * DCH + ch * 8) = v;
        }
    } else {
        float gv[4], bv[4], wl[4];
        #pragma unroll
        for (int nc = 0; nc < 4; ++nc) {
            const int col = wv * 64 + nc * 16 + cl;
            gv[nc] = gam[col]; bv[nc] = bet[col]; wl[nc] = Wl[col];
        }
        float* red2 = (float*)(lds + RED2_OFF);
        #pragma unroll
        for (int mr = 0; mr < 4; ++mr) {
            #pragma unroll
            for (int rg = 0; rg < 4; ++rg) {
                const int r = mr * 16 + q * 4 + rg;
                const float2 ms = *(const float2*)(stats + r * 2);
                float p = 0.f;
                #pragma unroll
                for (int nc = 0; nc < 4; ++nc) {
                    float v = (acc[mr][nc][rg] - ms.x) * ms.y * gv[nc] + bv[nc];
                    p += fmaxf(v, 0.f) * wl[nc];
                }
                #pragma unroll
                for (int m = 1; m < 16; m <<= 1) p += __shfl_xor(p, m, 64);
                if (cl == 0) red2[r * 4 + wv] = p;
            }
        }
        __syncthreads();
        if (tid < 64) {
            float d = red2[tid*4] + red2[tid*4+1] + red2[tid*4+2] + red2[tid*4+3] + bl[0];
            d *= mask[m0 + tid];
            ((float*)Y)[m0 + tid] = fmaxf(d, 0.f);
        }
    }
}

// ---------------------------------------------------------------------------
// Length regulation: 64 frames/block, binary search + coalesced gather-copy.
// ---------------------------------------------------------------------------
__global__ __launch_bounds__(256) void regulate_kernel(
    const float* __restrict__ enc,   // [BATCH][SEQ][256]
    const int*  __restrict__ cum,    // [BATCH][SEQ]
    float* __restrict__ out,         // [BATCH][TMAX][256]
    float* __restrict__ pos)         // [BATCH][TMAX]
{
    const int r   = blockIdx.x;      // 0..2047
    const int b   = r >> 6;
    const int t0  = (r & 63) * 64;
    const int tid = threadIdx.x;
    __shared__ int sidx[64];
    __shared__ int svalid[64];

    const int* c = cum + b * SEQ;
    if (tid < 64) {
        const int t = t0 + tid;
        const int total = c[SEQ - 1];
        int lo = 0, hi = SEQ;
        while (lo < hi) {
            const int mid = (lo + hi) >> 1;
            if (c[mid] <= t) lo = mid + 1; else hi = mid;
        }
        const int valid = (t < total) ? 1 : 0;
        sidx[tid]   = lo < (SEQ - 1) ? lo : (SEQ - 1);
        svalid[tid] = valid;
        pos[b * TMAX + t] = valid ? (float)(t + 1) : 0.f;
    }
    __syncthreads();

    const int f4 = (tid & 63) * 4;
    const int rg = tid >> 6;
    #pragma unroll
    for (int g = 0; g < 16; ++g) {
        const int tt = g * 4 + rg;
        float4 v = make_float4(0.f, 0.f, 0.f, 0.f);
        if (svalid[tt])
            v = *reinterpret_cast<const float4*>(enc + (size_t)(b * SEQ + sidx[tt]) * 256 + f4);
        *reinterpret_cast<float4*>(out + (size_t)(b * TMAX + t0 + tt) * 256 + f4) = v;
    }
}

// ---------------------------------------------------------------------------
extern "C" void kernel_launch(void* const* d_in, const int* in_sizes, int n_in,
                              void* d_out, int out_size, void* d_ws, size_t ws_size,
                              hipStream_t stream) {
    const float* enc   = (const float*)d_in[0];
    const float* mask  = (const float*)d_in[1];
    const int*   target= (const int*)  d_in[2];
    const float* W1    = (const float*)d_in[4];
    const float* b1    = (const float*)d_in[5];
    const float* g1    = (const float*)d_in[6];
    const float* beta1 = (const float*)d_in[7];
    const float* W2    = (const float*)d_in[8];
    const float* b2    = (const float*)d_in[9];
    const float* g2    = (const float*)d_in[10];
    const float* beta2 = (const float*)d_in[11];
    const float* Wl    = (const float*)d_in[12];
    const float* bl    = (const float*)d_in[13];

    float* outF = (float*)d_out;
    float* out_main = outF;                               // 32*4096*256
    float* out_pos  = outF + (size_t)BATCH * TMAX * DCH;  // 32*4096
    float* out_dur  = out_pos + (size_t)BATCH * TMAX;     // 32*1024

    char* ws = (char*)d_ws;
    short* h1  = (short*)ws;                                    // 16 MB bf16
    short* Wp1 = (short*)(ws + (size_t)MROWS * DCH * 2);
    short* Wp2 = Wp1 + WP_SHORTS;
    int*   cum = (int*)(Wp2 + WP_SHORTS);

    prep_kernel<<<80, 256, 0, stream>>>(W1, W2, Wp1, Wp2, target, cum);
    conv_mfma<false><<<MROWS / 64, 256, 0, stream>>>(
        enc, mask, Wp1, b1, g1, beta1, nullptr, nullptr, h1);
    conv_mfma<true><<<MROWS / 64, 256, 0, stream>>>(
        h1, mask, Wp2, b2, g2, beta2, Wl, bl, out_dur);
    regulate_kernel<<<2048, 256, 0, stream>>>(enc, cum, out_main, out_pos);
}

// Round 5
// 74.167 us; speedup vs baseline: 1.5821x; 1.1090x over previous
//
#include <hip/hip_runtime.h>
#include <hip/hip_bf16.h>

#define BATCH 32
#define SEQ   1024
#define DCH   256
#define TMAX  4096
#define MROWS (BATCH * SEQ)
#define EPS   1e-5f

typedef __attribute__((ext_vector_type(8))) short s16x8;   // 8 bf16 in 4 VGPRs
typedef __attribute__((ext_vector_type(4))) float f32x4;

#define NSTEPS 24
// Wp layout: [s][wv][nc][lane] 16B chunks -> short offset
//   s*8192 + wv*2048 + nc*512 + lane*8      (lane = q*16+cl)
#define WP_SHORTS (NSTEPS * 8192)            // 393216 B / layer

#define XST_B   33792                        // 66 rows x 512 B  (X tile)
#define RED_OFF   33792                      // [64][4][2] f32 = 2048 B
#define STATS_OFF 35840                      // [64][2]   f32 = 512 B
#define RED2_OFF  36352                      // [64][4]   f32 = 1024 B
#define LDS_TOTAL 37376                      // 37.4 KB -> 4 blocks/CU by LDS
#define XT2_STRIDE 528                       // transpose-out row stride (bytes)

#define CONV_BLOCKS 512
#define REG_PER_KERNEL 1024
#define GRID_TOTAL (CONV_BLOCKS + REG_PER_KERNEL)   // conv first, then regulate

__device__ __forceinline__ short f2bf(float f) {
    union { float f; unsigned u; } x; x.f = f;
    unsigned r = x.u + 0x7fffu + ((x.u >> 16) & 1u);   // RNE
    return (short)(r >> 16);
}

// ---------------------------------------------------------------------------
// Prep: blocks 0..47 -> weight bf16 repack (coalesced B-frag layout);
//       blocks 48..79 -> per-batch cumsum of reps = target + 1.
// ---------------------------------------------------------------------------
__global__ __launch_bounds__(256) void prep_kernel(
    const float* __restrict__ W1, const float* __restrict__ W2,
    short* __restrict__ Wp1, short* __restrict__ Wp2,
    const int* __restrict__ target, int* __restrict__ cum)
{
    const int bx  = blockIdx.x;
    const int tid = threadIdx.x;
    if (bx < 48) {
        const int s = bx % NSTEPS;
        const float* W = (bx < NSTEPS) ? W1 : W2;
        short* out = (bx < NSTEPS) ? Wp1 : Wp2;
        const int n  = tid;                  // output col 0..255
        const int wv = n >> 6;
        const int nc = (n >> 4) & 3;
        const int cl = n & 15;
        const int ko = s >> 3;
        const int cb = (s & 7) * 32;
        #pragma unroll
        for (int q = 0; q < 4; ++q) {
            short v[8];
            #pragma unroll
            for (int j = 0; j < 8; ++j)
                v[j] = f2bf(W[(size_t)(ko * 256 + cb + q * 8 + j) * 256 + n]);
            short* dst = out + s * 8192 + wv * 2048 + nc * 512 + (q * 16 + cl) * 8;
            *(s16x8*)dst = *(const s16x8*)v;
        }
    } else {
        const int b = bx - 48;
        const int base = b * SEQ + tid * 4;
        int vals[4];
        int s = 0;
        #pragma unroll
        for (int j = 0; j < 4; ++j) {
            s += target[base + j] + 1;   // alpha == 1.0 -> reps = target + 1
            vals[j] = s;
        }
        const int lane = tid & 63;
        int tot = s;
        #pragma unroll
        for (int off = 1; off < 64; off <<= 1) {
            int t = __shfl_up(tot, off, 64);
            if (lane >= off) tot += t;
        }
        __shared__ int wsum[4];
        const int wid = tid >> 6;
        if (lane == 63) wsum[wid] = tot;
        __syncthreads();
        int woff = 0;
        for (int w = 0; w < wid; ++w) woff += wsum[w];
        const int thr_excl = tot - s + woff;
        #pragma unroll
        for (int j = 0; j < 4; ++j) cum[base + j] = thr_excl + vals[j];
    }
}

// ---------------------------------------------------------------------------
// Fused kernel: blocks [0,512) conv1d+LN(+head) MFMA; blocks [512,1536)
// length-regulate (64 output frames x 256 ch each). Conv blocks dispatch
// first so they grab 2 slots/CU; regulate blocks churn the 3rd slot,
// overlapping HBM writes with MFMA compute.
// ---------------------------------------------------------------------------
template <bool HEAD>
__global__ __launch_bounds__(256, 3) void conv_reg(
    const void* __restrict__ Xsrc,      // f32 enc (HEAD=0) or bf16 h1 (HEAD=1)
    const float* __restrict__ mask,     // [MROWS]
    const short* __restrict__ Wp,       // repacked bf16 weights
    const float* __restrict__ bias,
    const float* __restrict__ gam,
    const float* __restrict__ bet,
    const float* __restrict__ Wl,       // [256] (HEAD only)
    const float* __restrict__ bl,       // [1]   (HEAD only)
    void* __restrict__ Y,
    const float* __restrict__ enc,      // [BATCH][SEQ][256] f32
    const int*  __restrict__ cum,       // [BATCH][SEQ]
    float* __restrict__ out_main,       // [BATCH][TMAX][256]
    float* __restrict__ out_pos)        // [BATCH][TMAX]
{
    __shared__ __align__(16) char lds[LDS_TOTAL];
    const int tid = threadIdx.x;
    const int bx  = blockIdx.x;

    if (bx >= CONV_BLOCKS) {
        // =================== length-regulate block ===================
        const int r  = (bx - CONV_BLOCKS) + (HEAD ? REG_PER_KERNEL : 0); // 0..2047
        const int b  = r >> 6;
        const int t0 = (r & 63) * 64;
        int* sidx   = (int*)lds;
        int* svalid = (int*)(lds + 256);
        const int* c = cum + b * SEQ;
        if (tid < 64) {
            const int t = t0 + tid;
            const int total = c[SEQ - 1];
            int lo = 0, hi = SEQ;
            while (lo < hi) {
                const int mid = (lo + hi) >> 1;
                if (c[mid] <= t) lo = mid + 1; else hi = mid;
            }
            const int valid = (t < total) ? 1 : 0;
            sidx[tid]   = lo < (SEQ - 1) ? lo : (SEQ - 1);
            svalid[tid] = valid;
            out_pos[b * TMAX + t] = valid ? (float)(t + 1) : 0.f;
        }
        __syncthreads();
        const int f4 = (tid & 63) * 4;
        const int rg = tid >> 6;
        #pragma unroll
        for (int g = 0; g < 16; ++g) {
            const int tt = g * 4 + rg;
            float4 v = make_float4(0.f, 0.f, 0.f, 0.f);
            if (svalid[tt])
                v = *reinterpret_cast<const float4*>(enc + (size_t)(b * SEQ + sidx[tt]) * 256 + f4);
            *reinterpret_cast<float4*>(out_main + (size_t)(b * TMAX + t0 + tt) * 256 + f4) = v;
        }
        return;
    }

    // ======================= conv block =======================
    char* const Xst = lds;

    const int lane = tid & 63;
    const int wv   = tid >> 6;          // wave 0..3 -> cols wv*64..+63
    const int cl   = lane & 15;
    const int q    = lane >> 4;
    const int m0   = bx * 64;
    const int blo  = m0 & ~(SEQ - 1);
    const int bhi  = blo + SEQ;

    // ---- stage X tile: rows m0-1 .. m0+64 (halo), XOR-swizzled 16B chunks ----
    for (int t = tid; t < 66 * 32; t += 256) {
        const int r  = t >> 5;
        const int ch = t & 31;
        const int grow = m0 - 1 + r;
        s16x8 v = {0, 0, 0, 0, 0, 0, 0, 0};
        if (grow >= blo && grow < bhi) {
            if (!HEAD) {
                const float* xf = (const float*)Xsrc + (size_t)grow * DCH + ch * 8;
                const float4 f0 = *(const float4*)xf;
                const float4 f1 = *(const float4*)(xf + 4);
                const float mk = mask[grow];
                v[0] = f2bf(f0.x * mk); v[1] = f2bf(f0.y * mk);
                v[2] = f2bf(f0.z * mk); v[3] = f2bf(f0.w * mk);
                v[4] = f2bf(f1.x * mk); v[5] = f2bf(f1.y * mk);
                v[6] = f2bf(f1.z * mk); v[7] = f2bf(f1.w * mk);
            } else {
                v = *(const s16x8*)((const char*)Xsrc + (size_t)grow * 512 + ch * 16);
            }
        }
        *(s16x8*)(Xst + r * 512 + ((ch ^ (r & 7)) << 4)) = v;
    }

    // ---- init acc with conv bias ----
    f32x4 acc[4][4];
    #pragma unroll
    for (int nc = 0; nc < 4; ++nc) {
        const float b = bias[wv * 64 + nc * 16 + cl];
        #pragma unroll
        for (int mr = 0; mr < 4; ++mr) acc[mr][nc] = (f32x4){b, b, b, b};
    }

    // ---- B-frag prefetch for step 0 (global, coalesced dwordx4) ----
    const short* wbase = Wp + wv * 2048 + lane * 8;
    s16x8 bb[4];
    #pragma unroll
    for (int nc = 0; nc < 4; ++nc)
        bb[nc] = *(const s16x8*)(wbase + nc * 512);

    __syncthreads();   // X tile ready; only barrier before epilogue

    // ---- K loop: 24 steps, no barriers, B prefetched one step ahead ----
    for (int s = 0; s < NSTEPS; ++s) {
        const int sp = (s + 1 < NSTEPS) ? s + 1 : s;
        s16x8 bn[4];
        #pragma unroll
        for (int nc = 0; nc < 4; ++nc)
            bn[nc] = *(const s16x8*)(wbase + sp * 8192 + nc * 512);
        const int ko  = s >> 3;
        const int chb = (s & 7) * 4 + q;
        s16x8 a[4];
        #pragma unroll
        for (int mr = 0; mr < 4; ++mr) {
            const int tr = mr * 16 + cl + ko;
            a[mr] = *(const s16x8*)(Xst + tr * 512 + ((chb ^ (tr & 7)) << 4));
        }
        #pragma unroll
        for (int mr = 0; mr < 4; ++mr)
            #pragma unroll
            for (int nc = 0; nc < 4; ++nc)
                acc[mr][nc] = __builtin_amdgcn_mfma_f32_16x16x32_bf16(
                    a[mr], bb[nc], acc[mr][nc], 0, 0, 0);
        #pragma unroll
        for (int nc = 0; nc < 4; ++nc) bb[nc] = bn[nc];
    }

    // ---- LayerNorm stats: 16-lane shfl + cross-wave LDS reduction ----
    float* red   = (float*)(lds + RED_OFF);
    float* stats = (float*)(lds + STATS_OFF);
    #pragma unroll
    for (int mr = 0; mr < 4; ++mr) {
        #pragma unroll
        for (int rg = 0; rg < 4; ++rg) {
            float s1 = 0.f, s2 = 0.f;
            #pragma unroll
            for (int nc = 0; nc < 4; ++nc) {
                const float v = acc[mr][nc][rg];
                s1 += v; s2 += v * v;
            }
            #pragma unroll
            for (int m = 1; m < 16; m <<= 1) {
                s1 += __shfl_xor(s1, m, 64);
                s2 += __shfl_xor(s2, m, 64);
            }
            if (cl == 0) {
                const int r = mr * 16 + q * 4 + rg;
                red[(r * 4 + wv) * 2]     = s1;
                red[(r * 4 + wv) * 2 + 1] = s2;
            }
        }
    }
    __syncthreads();   // also: all waves done reading Xst
    if (tid < 64) {
        const float s1 = red[tid*8] + red[tid*8+2] + red[tid*8+4] + red[tid*8+6];
        const float s2 = red[tid*8+1] + red[tid*8+3] + red[tid*8+5] + red[tid*8+7];
        const float mean = s1 * (1.f / 256.f);
        const float var  = s2 * (1.f / 256.f) - mean * mean;
        stats[tid * 2]     = mean;
        stats[tid * 2 + 1] = rsqrtf(var + EPS);
    }
    __syncthreads();

    if (!HEAD) {
        float gv[4], bv[4];
        #pragma unroll
        for (int nc = 0; nc < 4; ++nc) {
            const int col = wv * 64 + nc * 16 + cl;
            gv[nc] = gam[col]; bv[nc] = bet[col];
        }
        // normalized bf16 -> LDS transpose buffer (reuses Xst region)
        #pragma unroll
        for (int mr = 0; mr < 4; ++mr) {
            #pragma unroll
            for (int rg = 0; rg < 4; ++rg) {
                const int r = mr * 16 + q * 4 + rg;
                const float2 ms = *(const float2*)(stats + r * 2);
                #pragma unroll
                for (int nc = 0; nc < 4; ++nc) {
                    const int col = wv * 64 + nc * 16 + cl;
                    float v = (acc[mr][nc][rg] - ms.x) * ms.y * gv[nc] + bv[nc];
                    *(short*)(lds + r * XT2_STRIDE + col * 2) = f2bf(fmaxf(v, 0.f));
                }
            }
        }
        __syncthreads();
        // coalesced 16B copy-out
        short* y = (short*)Y;
        #pragma unroll
        for (int i = 0; i < 8; ++i) {
            const int t  = tid + i * 256;     // 0..2047
            const int r  = t >> 5;
            const int ch = t & 31;
            const s16x8 v = *(const s16x8*)(lds + r * XT2_STRIDE + ch * 16);
            *(s16x8*)(y + (size_t)(m0 + r) * DCH + ch * 8) = v;
        }
    } else {
        float gv[4], bv[4], wl[4];
        #pragma unroll
        for (int nc = 0; nc < 4; ++nc) {
            const int col = wv * 64 + nc * 16 + cl;
            gv[nc] = gam[col]; bv[nc] = bet[col]; wl[nc] = Wl[col];
        }
        float* red2 = (float*)(lds + RED2_OFF);
        #pragma unroll
        for (int mr = 0; mr < 4; ++mr) {
            #pragma unroll
            for (int rg = 0; rg < 4; ++rg) {
                const int r = mr * 16 + q * 4 + rg;
                const float2 ms = *(const float2*)(stats + r * 2);
                float p = 0.f;
                #pragma unroll
                for (int nc = 0; nc < 4; ++nc) {
                    float v = (acc[mr][nc][rg] - ms.x) * ms.y * gv[nc] + bv[nc];
                    p += fmaxf(v, 0.f) * wl[nc];
                }
                #pragma unroll
                for (int m = 1; m < 16; m <<= 1) p += __shfl_xor(p, m, 64);
                if (cl == 0) red2[r * 4 + wv] = p;
            }
        }
        __syncthreads();
        if (tid < 64) {
            float d = red2[tid*4] + red2[tid*4+1] + red2[tid*4+2] + red2[tid*4+3] + bl[0];
            d *= mask[m0 + tid];
            ((float*)Y)[m0 + tid] = fmaxf(d, 0.f);
        }
    }
}

// ---------------------------------------------------------------------------
extern "C" void kernel_launch(void* const* d_in, const int* in_sizes, int n_in,
                              void* d_out, int out_size, void* d_ws, size_t ws_size,
                              hipStream_t stream) {
    const float* enc   = (const float*)d_in[0];
    const float* mask  = (const float*)d_in[1];
    const int*   target= (const int*)  d_in[2];
    const float* W1    = (const float*)d_in[4];
    const float* b1    = (const float*)d_in[5];
    const float* g1    = (const float*)d_in[6];
    const float* beta1 = (const float*)d_in[7];
    const float* W2    = (const float*)d_in[8];
    const float* b2    = (const float*)d_in[9];
    const float* g2    = (const float*)d_in[10];
    const float* beta2 = (const float*)d_in[11];
    const float* Wl    = (const float*)d_in[12];
    const float* bl    = (const float*)d_in[13];

    float* outF = (float*)d_out;
    float* out_main = outF;                               // 32*4096*256
    float* out_pos  = outF + (size_t)BATCH * TMAX * DCH;  // 32*4096
    float* out_dur  = out_pos + (size_t)BATCH * TMAX;     // 32*1024

    char* ws = (char*)d_ws;
    short* h1  = (short*)ws;                                    // 16 MB bf16
    short* Wp1 = (short*)(ws + (size_t)MROWS * DCH * 2);
    short* Wp2 = Wp1 + WP_SHORTS;
    int*   cum = (int*)(Wp2 + WP_SHORTS);

    prep_kernel<<<80, 256, 0, stream>>>(W1, W2, Wp1, Wp2, target, cum);
    conv_reg<false><<<GRID_TOTAL, 256, 0, stream>>>(
        enc, mask, Wp1, b1, g1, beta1, nullptr, nullptr, h1,
        enc, cum, out_main, out_pos);
    conv_reg<true><<<GRID_TOTAL, 256, 0, stream>>>(
        h1, mask, Wp2, b2, g2, beta2, Wl, bl, out_dur,
        enc, cum, out_main, out_pos);
}

// Round 6
// 72.874 us; speedup vs baseline: 1.6101x; 1.0177x over previous
//
#include <hip/hip_runtime.h>
#include <hip/hip_bf16.h>

#define BATCH 32
#define SEQ   1024
#define DCH   256
#define TMAX  4096
#define MROWS (BATCH * SEQ)
#define EPS   1e-5f

typedef __attribute__((ext_vector_type(8))) short s16x8;   // 8 bf16 in 4 VGPRs
typedef __attribute__((ext_vector_type(4))) float f32x4;

#define NSTEPS 24
// Wp layout: [s][wv][nc][lane] 16B chunks -> short offset
//   s*8192 + wv*2048 + nc*512 + lane*8      (lane = q*16+cl)
#define WP_SHORTS (NSTEPS * 8192)            // 393216 B / layer

// LDS map (conv path):
//   [0, 41984)  X tile: 82 rows x 512 B (row xi <-> global m0-2+xi), XOR-swz
//   after GEMM1 (X dead):
//     [0,    2560)  red1  [80 rows][4 waves][2] f32 (only rows<66 written)
//     [2560, 3200)  stats1[80 rows][2] f32 (rows<66)
//     [4096, 38912) h1 tile: 68 rows x 512 B bf16 (row hr <-> global m0-1+hr)
//   after GEMM2 (epilogue2):
//     [0,    2048)  red2 [64][4][2] ; [2048,2560) stats2 [64][2]
//     [2560, 3584)  wred [64][4]
#define XST_B     41984
#define H1_OFF    4096
#define STATS1_OFF 2560
#define STATS2_OFF 2048
#define WRED_OFF   2560
#define LDS_TOTAL  41984                     // 42 KB -> 3 blocks/CU

#define CONV_BLOCKS 512
#define REG_BLOCKS  2048
#define GRID_TOTAL  (CONV_BLOCKS + REG_BLOCKS)   // conv first

__device__ __forceinline__ short f2bf(float f) {
    union { float f; unsigned u; } x; x.f = f;
    unsigned r = x.u + 0x7fffu + ((x.u >> 16) & 1u);   // RNE
    return (short)(r >> 16);
}

// ---------------------------------------------------------------------------
// Prep: blocks 0..47 -> weight bf16 repack; blocks 48..79 -> cumsum(target+1).
// ---------------------------------------------------------------------------
__global__ __launch_bounds__(256) void prep_kernel(
    const float* __restrict__ W1, const float* __restrict__ W2,
    short* __restrict__ Wp1, short* __restrict__ Wp2,
    const int* __restrict__ target, int* __restrict__ cum)
{
    const int bx  = blockIdx.x;
    const int tid = threadIdx.x;
    if (bx < 48) {
        const int s = bx % NSTEPS;
        const float* W = (bx < NSTEPS) ? W1 : W2;
        short* out = (bx < NSTEPS) ? Wp1 : Wp2;
        const int n  = tid;                  // output col 0..255
        const int wv = n >> 6;
        const int nc = (n >> 4) & 3;
        const int cl = n & 15;
        const int ko = s >> 3;
        const int cb = (s & 7) * 32;
        #pragma unroll
        for (int q = 0; q < 4; ++q) {
            short v[8];
            #pragma unroll
            for (int j = 0; j < 8; ++j)
                v[j] = f2bf(W[(size_t)(ko * 256 + cb + q * 8 + j) * 256 + n]);
            short* dst = out + s * 8192 + wv * 2048 + nc * 512 + (q * 16 + cl) * 8;
            *(s16x8*)dst = *(const s16x8*)v;
        }
    } else {
        const int b = bx - 48;
        const int base = b * SEQ + tid * 4;
        int vals[4];
        int s = 0;
        #pragma unroll
        for (int j = 0; j < 4; ++j) {
            s += target[base + j] + 1;   // alpha == 1.0 -> reps = target + 1
            vals[j] = s;
        }
        const int lane = tid & 63;
        int tot = s;
        #pragma unroll
        for (int off = 1; off < 64; off <<= 1) {
            int t = __shfl_up(tot, off, 64);
            if (lane >= off) tot += t;
        }
        __shared__ int wsum[4];
        const int wid = tid >> 6;
        if (lane == 63) wsum[wid] = tot;
        __syncthreads();
        int woff = 0;
        for (int w = 0; w < wid; ++w) woff += wsum[w];
        const int thr_excl = tot - s + woff;
        #pragma unroll
        for (int j = 0; j < 4; ++j) cum[base + j] = thr_excl + vals[j];
    }
}

// ---------------------------------------------------------------------------
// Mega-fused kernel:
//   blocks [0,512):    conv1+LN+ReLU (h1 in LDS) -> conv2+LN+ReLU+head -> dur
//   blocks [512,2560): length-regulate (64 output frames x 256 ch each)
// ---------------------------------------------------------------------------
__global__ __launch_bounds__(256, 3) void fused_kernel(
    const float* __restrict__ enc,      // [MROWS][256] f32
    const float* __restrict__ mask,     // [MROWS]
    const short* __restrict__ Wp1,      // repacked bf16 weights, layer 1
    const short* __restrict__ Wp2,      // layer 2
    const float* __restrict__ b1, const float* __restrict__ g1, const float* __restrict__ be1,
    const float* __restrict__ b2, const float* __restrict__ g2, const float* __restrict__ be2,
    const float* __restrict__ Wl, const float* __restrict__ bl,
    float* __restrict__ out_dur,        // [MROWS]
    const int*  __restrict__ cum,       // [BATCH][SEQ]
    float* __restrict__ out_main,       // [BATCH][TMAX][256]
    float* __restrict__ out_pos)        // [BATCH][TMAX]
{
    __shared__ __align__(16) char lds[LDS_TOTAL];
    const int tid = threadIdx.x;
    const int bx  = blockIdx.x;

    if (bx >= CONV_BLOCKS) {
        // =================== length-regulate block ===================
        const int r  = bx - CONV_BLOCKS;           // 0..2047
        const int b  = r >> 6;
        const int t0 = (r & 63) * 64;
        int* sidx   = (int*)lds;
        int* svalid = (int*)(lds + 256);
        const int* c = cum + b * SEQ;
        if (tid < 64) {
            const int t = t0 + tid;
            const int total = c[SEQ - 1];
            int lo = 0, hi = SEQ;
            while (lo < hi) {
                const int mid = (lo + hi) >> 1;
                if (c[mid] <= t) lo = mid + 1; else hi = mid;
            }
            const int valid = (t < total) ? 1 : 0;
            sidx[tid]   = lo < (SEQ - 1) ? lo : (SEQ - 1);
            svalid[tid] = valid;
            out_pos[b * TMAX + t] = valid ? (float)(t + 1) : 0.f;
        }
        __syncthreads();
        const int f4 = (tid & 63) * 4;
        const int rg = tid >> 6;
        #pragma unroll
        for (int g = 0; g < 16; ++g) {
            const int tt = g * 4 + rg;
            float4 v = make_float4(0.f, 0.f, 0.f, 0.f);
            if (svalid[tt])
                v = *reinterpret_cast<const float4*>(enc + (size_t)(b * SEQ + sidx[tt]) * 256 + f4);
            *reinterpret_cast<float4*>(out_main + (size_t)(b * TMAX + t0 + tt) * 256 + f4) = v;
        }
        return;
    }

    // ======================= conv block =======================
    char* const Xst = lds;

    const int lane = tid & 63;
    const int wv   = tid >> 6;          // wave 0..3 -> cols wv*64..+63
    const int cl   = lane & 15;
    const int q    = lane >> 4;
    const int m0   = bx * 64;
    const int blo  = m0 & ~(SEQ - 1);
    const int bhi  = blo + SEQ;

    // ---- stage X tile: rows m0-2 .. m0+79 (xi 0..81), XOR-swz 16B chunks ----
    for (int t = tid; t < 82 * 32; t += 256) {
        const int r  = t >> 5;
        const int ch = t & 31;
        const int grow = m0 - 2 + r;
        s16x8 v = {0, 0, 0, 0, 0, 0, 0, 0};
        if (grow >= blo && grow < bhi) {
            const float* xf = enc + (size_t)grow * DCH + ch * 8;
            const float4 f0 = *(const float4*)xf;
            const float4 f1 = *(const float4*)(xf + 4);
            const float mk = mask[grow];
            v[0] = f2bf(f0.x * mk); v[1] = f2bf(f0.y * mk);
            v[2] = f2bf(f0.z * mk); v[3] = f2bf(f0.w * mk);
            v[4] = f2bf(f1.x * mk); v[5] = f2bf(f1.y * mk);
            v[6] = f2bf(f1.z * mk); v[7] = f2bf(f1.w * mk);
        }
        *(s16x8*)(Xst + r * 512 + ((ch ^ (r & 7)) << 4)) = v;
    }

    // ---- GEMM1 acc init with bias1 ----
    f32x4 acc1[5][4];
    #pragma unroll
    for (int nc = 0; nc < 4; ++nc) {
        const float b = b1[wv * 64 + nc * 16 + cl];
        #pragma unroll
        for (int mr = 0; mr < 5; ++mr) acc1[mr][nc] = (f32x4){b, b, b, b};
    }

    const short* wb1 = Wp1 + wv * 2048 + lane * 8;
    const short* wb2 = Wp2 + wv * 2048 + lane * 8;
    s16x8 bb[4];
    #pragma unroll
    for (int nc = 0; nc < 4; ++nc) bb[nc] = *(const s16x8*)(wb1 + nc * 512);

    __syncthreads();   // X tile ready

    // ---- GEMM1 K loop: h1 rows hr = tile row (global m0-1+hr) ----
    for (int s = 0; s < NSTEPS; ++s) {
        const int sp = (s + 1 < NSTEPS) ? s + 1 : s;
        s16x8 bn[4];
        #pragma unroll
        for (int nc = 0; nc < 4; ++nc)
            bn[nc] = *(const s16x8*)(wb1 + sp * 8192 + nc * 512);
        const int ko  = s >> 3;
        const int chb = (s & 7) * 4 + q;
        s16x8 a[5];
        #pragma unroll
        for (int mr = 0; mr < 5; ++mr) {
            const int tr = mr * 16 + cl + ko;            // X row xi (0..81)
            a[mr] = *(const s16x8*)(Xst + tr * 512 + ((chb ^ (tr & 7)) << 4));
        }
        #pragma unroll
        for (int mr = 0; mr < 5; ++mr)
            #pragma unroll
            for (int nc = 0; nc < 4; ++nc)
                acc1[mr][nc] = __builtin_amdgcn_mfma_f32_16x16x32_bf16(
                    a[mr], bb[nc], acc1[mr][nc], 0, 0, 0);
        #pragma unroll
        for (int nc = 0; nc < 4; ++nc) bb[nc] = bn[nc];
    }

    // prefetch GEMM2 step-0 B frags early (hide L2 latency under epilogue 1)
    s16x8 bb2[4];
    #pragma unroll
    for (int nc = 0; nc < 4; ++nc) bb2[nc] = *(const s16x8*)(wb2 + nc * 512);

    // ---- LN1 stats (rows hr < 66) ----
    float* red1 = (float*)lds;
    float* st1  = (float*)(lds + STATS1_OFF);
    __syncthreads();   // all waves done reading X
    #pragma unroll
    for (int mr = 0; mr < 5; ++mr) {
        #pragma unroll
        for (int rg = 0; rg < 4; ++rg) {
            float s1 = 0.f, s2 = 0.f;
            #pragma unroll
            for (int nc = 0; nc < 4; ++nc) {
                const float v = acc1[mr][nc][rg];
                s1 += v; s2 += v * v;
            }
            #pragma unroll
            for (int m = 1; m < 16; m <<= 1) {
                s1 += __shfl_xor(s1, m, 64);
                s2 += __shfl_xor(s2, m, 64);
            }
            const int hr = mr * 16 + q * 4 + rg;
            if (cl == 0 && hr < 66) {
                red1[(hr * 4 + wv) * 2]     = s1;
                red1[(hr * 4 + wv) * 2 + 1] = s2;
            }
        }
    }
    __syncthreads();
    if (tid < 66) {
        const float s1 = red1[tid*8] + red1[tid*8+2] + red1[tid*8+4] + red1[tid*8+6];
        const float s2 = red1[tid*8+1] + red1[tid*8+3] + red1[tid*8+5] + red1[tid*8+7];
        const float mean = s1 * (1.f / 256.f);
        const float var  = s2 * (1.f / 256.f) - mean * mean;
        st1[tid * 2]     = mean;
        st1[tid * 2 + 1] = rsqrtf(var + EPS);
    }
    __syncthreads();

    // ---- write h1 (LN+ReLU, bf16) into LDS; zero out-of-batch rows ----
    {
        float gv[4], bv[4];
        #pragma unroll
        for (int nc = 0; nc < 4; ++nc) {
            const int col = wv * 64 + nc * 16 + cl;
            gv[nc] = g1[col]; bv[nc] = be1[col];
        }
        #pragma unroll
        for (int mr = 0; mr < 5; ++mr) {
            #pragma unroll
            for (int rg = 0; rg < 4; ++rg) {
                const int hr = mr * 16 + q * 4 + rg;
                if (hr < 66) {
                    const int grow = m0 - 1 + hr;
                    const bool inb = (grow >= blo) && (grow < bhi);
                    const float2 ms = *(const float2*)(st1 + hr * 2);
                    #pragma unroll
                    for (int nc = 0; nc < 4; ++nc) {
                        const int col = wv * 64 + nc * 16 + cl;
                        float v = (acc1[mr][nc][rg] - ms.x) * ms.y * gv[nc] + bv[nc];
                        v = inb ? fmaxf(v, 0.f) : 0.f;
                        *(short*)(lds + H1_OFF + hr * 512 +
                                  ((((col >> 3) ^ (hr & 7)) << 4) + (col & 7) * 2)) = f2bf(v);
                    }
                }
            }
        }
    }
    __syncthreads();   // h1 ready

    // ---- GEMM2 K loop (A from h1 LDS, rows tr2 0..65) ----
    f32x4 acc2[4][4];
    #pragma unroll
    for (int nc = 0; nc < 4; ++nc) {
        const float b = b2[wv * 64 + nc * 16 + cl];
        #pragma unroll
        for (int mr = 0; mr < 4; ++mr) acc2[mr][nc] = (f32x4){b, b, b, b};
    }
    for (int s = 0; s < NSTEPS; ++s) {
        const int sp = (s + 1 < NSTEPS) ? s + 1 : s;
        s16x8 bn[4];
        #pragma unroll
        for (int nc = 0; nc < 4; ++nc)
            bn[nc] = *(const s16x8*)(wb2 + sp * 8192 + nc * 512);
        const int ko  = s >> 3;
        const int chb = (s & 7) * 4 + q;
        s16x8 a[4];
        #pragma unroll
        for (int mr = 0; mr < 4; ++mr) {
            const int tr = mr * 16 + cl + ko;            // h1 row (0..65)
            a[mr] = *(const s16x8*)(lds + H1_OFF + tr * 512 + ((chb ^ (tr & 7)) << 4));
        }
        #pragma unroll
        for (int mr = 0; mr < 4; ++mr)
            #pragma unroll
            for (int nc = 0; nc < 4; ++nc)
                acc2[mr][nc] = __builtin_amdgcn_mfma_f32_16x16x32_bf16(
                    a[mr], bb2[nc], acc2[mr][nc], 0, 0, 0);
        #pragma unroll
        for (int nc = 0; nc < 4; ++nc) bb2[nc] = bn[nc];
    }

    // ---- LN2 stats (rows 0..63 = global m0..m0+63) ----
    float* red2 = (float*)lds;
    float* st2  = (float*)(lds + STATS2_OFF);
    float* wred = (float*)(lds + WRED_OFF);
    __syncthreads();   // all waves done reading h1
    #pragma unroll
    for (int mr = 0; mr < 4; ++mr) {
        #pragma unroll
        for (int rg = 0; rg < 4; ++rg) {
            float s1 = 0.f, s2 = 0.f;
            #pragma unroll
            for (int nc = 0; nc < 4; ++nc) {
                const float v = acc2[mr][nc][rg];
                s1 += v; s2 += v * v;
            }
            #pragma unroll
            for (int m = 1; m < 16; m <<= 1) {
                s1 += __shfl_xor(s1, m, 64);
                s2 += __shfl_xor(s2, m, 64);
            }
            if (cl == 0) {
                const int r = mr * 16 + q * 4 + rg;
                red2[(r * 4 + wv) * 2]     = s1;
                red2[(r * 4 + wv) * 2 + 1] = s2;
            }
        }
    }
    __syncthreads();
    if (tid < 64) {
        const float s1 = red2[tid*8] + red2[tid*8+2] + red2[tid*8+4] + red2[tid*8+6];
        const float s2 = red2[tid*8+1] + red2[tid*8+3] + red2[tid*8+5] + red2[tid*8+7];
        const float mean = s1 * (1.f / 256.f);
        const float var  = s2 * (1.f / 256.f) - mean * mean;
        st2[tid * 2]     = mean;
        st2[tid * 2 + 1] = rsqrtf(var + EPS);
    }
    __syncthreads();

    // ---- head: relu(LN2) . Wl + bl, masked, relu -> dur ----
    {
        float gv[4], bv[4], wl[4];
        #pragma unroll
        for (int nc = 0; nc < 4; ++nc) {
            const int col = wv * 64 + nc * 16 + cl;
            gv[nc] = g2[col]; bv[nc] = be2[col]; wl[nc] = Wl[col];
        }
        #pragma unroll
        for (int mr = 0; mr < 4; ++mr) {
            #pragma unroll
            for (int rg = 0; rg < 4; ++rg) {
                const int r = mr * 16 + q * 4 + rg;
                const float2 ms = *(const float2*)(st2 + r * 2);
                float p = 0.f;
                #pragma unroll
                for (int nc = 0; nc < 4; ++nc) {
                    float v = (acc2[mr][nc][rg] - ms.x) * ms.y * gv[nc] + bv[nc];
                    p += fmaxf(v, 0.f) * wl[nc];
                }
                #pragma unroll
                for (int m = 1; m < 16; m <<= 1) p += __shfl_xor(p, m, 64);
                if (cl == 0) wred[r * 4 + wv] = p;
            }
        }
        __syncthreads();
        if (tid < 64) {
            float d = wred[tid*4] + wred[tid*4+1] + wred[tid*4+2] + wred[tid*4+3] + bl[0];
            d *= mask[m0 + tid];
            out_dur[m0 + tid] = fmaxf(d, 0.f);
        }
    }
}

// ---------------------------------------------------------------------------
extern "C" void kernel_launch(void* const* d_in, const int* in_sizes, int n_in,
                              void* d_out, int out_size, void* d_ws, size_t ws_size,
                              hipStream_t stream) {
    const float* enc   = (const float*)d_in[0];
    const float* mask  = (const float*)d_in[1];
    const int*   target= (const int*)  d_in[2];
    const float* W1    = (const float*)d_in[4];
    const float* b1    = (const float*)d_in[5];
    const float* g1    = (const float*)d_in[6];
    const float* beta1 = (const float*)d_in[7];
    const float* W2    = (const float*)d_in[8];
    const float* b2    = (const float*)d_in[9];
    const float* g2    = (const float*)d_in[10];
    const float* beta2 = (const float*)d_in[11];
    const float* Wl    = (const float*)d_in[12];
    const float* bl    = (const float*)d_in[13];

    float* outF = (float*)d_out;
    float* out_main = outF;                               // 32*4096*256
    float* out_pos  = outF + (size_t)BATCH * TMAX * DCH;  // 32*4096
    float* out_dur  = out_pos + (size_t)BATCH * TMAX;     // 32*1024

    char* ws = (char*)d_ws;
    short* Wp1 = (short*)ws;
    short* Wp2 = Wp1 + WP_SHORTS;
    int*   cum = (int*)(Wp2 + WP_SHORTS);

    prep_kernel<<<80, 256, 0, stream>>>(W1, W2, Wp1, Wp2, target, cum);
    fused_kernel<<<GRID_TOTAL, 256, 0, stream>>>(
        enc, mask, Wp1, Wp2,
        b1, g1, beta1, b2, g2, beta2, Wl, bl,
        out_dur, cum, out_main, out_pos);
}